// Round 8
// baseline (879.204 us; speedup 1.0000x reference)
//
#include <hip/hip_runtime.h>
#include <hip/hip_bf16.h>

typedef float f32x4 __attribute__((ext_vector_type(4)));
typedef __bf16 bf16x8 __attribute__((ext_vector_type(8)));
typedef __bf16 bf16x4 __attribute__((ext_vector_type(4)));

#define DEVI static __device__ __forceinline__

DEVI void glds16(const void* g, void* l) {
  __builtin_amdgcn_global_load_lds((__attribute__((address_space(1))) void*)g,
                                   (__attribute__((address_space(3))) void*)l, 16, 0, 0);
}

DEVI f32x4 load4(const float* p) { return *(const f32x4*)p; }
DEVI f32x4 load4(const __bf16* p) {
  bf16x4 v = *(const bf16x4*)p;
  f32x4 o = { (float)v[0], (float)v[1], (float)v[2], (float)v[3] };
  return o;
}
DEVI void store4(float* p, f32x4 v) { *(f32x4*)p = v; }
DEVI void store4(__bf16* p, f32x4 v) {
  bf16x4 o = { (__bf16)v[0], (__bf16)v[1], (__bf16)v[2], (__bf16)v[3] };
  *(bf16x4*)p = o;
}

// ---------------- weight fp32 -> bf16 ----------------
__global__ void cvt_bf16(const float* __restrict__ in, __bf16* __restrict__ out, int n4) {
  int i = blockIdx.x * 256 + threadIdx.x;
  if (i < n4) {
    f32x4 v = *(const f32x4*)(in + (size_t)i * 4);
    store4(out + (size_t)i * 4, v);
  }
}

// ---------------- LayerNorm over C=1024, one block per token ----------------
template <typename TIN, typename TOUT>
__global__ __launch_bounds__(256) void ln_kernel(const TIN* __restrict__ x,
    const float* __restrict__ gw, const float* __restrict__ bw,
    TOUT* __restrict__ out) {
  const size_t row = blockIdx.x;
  f32x4 v = load4(x + row * 1024 + threadIdx.x * 4);
  float s = v[0] + v[1] + v[2] + v[3];
  float q = v[0]*v[0] + v[1]*v[1] + v[2]*v[2] + v[3]*v[3];
#pragma unroll
  for (int o = 32; o > 0; o >>= 1) { s += __shfl_down(s, o); q += __shfl_down(q, o); }
  __shared__ float ss[4], qq[4];
  const int w = threadIdx.x >> 6, l = threadIdx.x & 63;
  if (l == 0) { ss[w] = s; qq[w] = q; }
  __syncthreads();
  s = ss[0] + ss[1] + ss[2] + ss[3];
  q = qq[0] + qq[1] + qq[2] + qq[3];
  const float mean = s * (1.0f / 1024.0f);
  const float var = q * (1.0f / 1024.0f) - mean * mean;
  const float rstd = rsqrtf(var + 1e-5f);
  f32x4 g4 = *(const f32x4*)(gw + threadIdx.x * 4);
  f32x4 b4 = *(const f32x4*)(bw + threadIdx.x * 4);
  f32x4 o;
#pragma unroll
  for (int j = 0; j < 4; ++j) o[j] = (v[j] - mean) * rstd * g4[j] + b4[j];
  store4(out + row * 1024 + threadIdx.x * 4, o);
}

// ---------------- time-shift mix -> bf16 ----------------
template <typename TIN>
__global__ __launch_bounds__(256) void mix_kernel(const TIN* __restrict__ x,
    const float* __restrict__ tm, const float* __restrict__ cm,
    __bf16* __restrict__ out) {
  const int idx = blockIdx.x * 256 + threadIdx.x;   // over B*T*C/4
  const int t = (idx >> 8) & 2047;                   // T=2048
  const int c = (idx & 255) * 4;                     // C/4=256
  const size_t base = ((size_t)(idx >> 8) << 10) + c;
  f32x4 xv = load4(x + base);
  f32x4 xm1 = {0.f, 0.f, 0.f, 0.f}, xp1 = {0.f, 0.f, 0.f, 0.f};
  if (t > 0)    xm1 = load4(x + base - 1024);
  if (t < 2047) xp1 = load4(x + base + 1024);
  f32x4 tm4 = *(const f32x4*)(tm + c);
  f32x4 cm4 = *(const f32x4*)(cm + c);
  f32x4 xc = (c < 512) ? xm1 : xp1;
  f32x4 o;
#pragma unroll
  for (int j = 0; j < 4; ++j)
    o[j] = xv[j] * tm4[j] + xm1[j] * (1.0f - tm4[j]) + xc[j] * cm4[j];
  store4(out + base, o);
}

// ---------------- WKV chunk-parallel scan (exact regroup of reference) ----------------
__global__ __launch_bounds__(256) void wkv_part(const __bf16* __restrict__ k,
    const __bf16* __restrict__ v, const float* __restrict__ td,
    float* __restrict__ scA, float* __restrict__ scB) {
  const int gid = blockIdx.x * 256 + threadIdx.x;   // b*32768 + j*1024 + c
  const int c = gid & 1023;
  const int j = (gid >> 10) & 31;
  const int b = gid >> 15;
  const float ed = expf(-expf(td[c]));
  float A = 0.f, Bv = 0.f;
  size_t off = ((size_t)(b * 2048 + j * 64) << 10) + c;
#pragma unroll 4
  for (int i = 0; i < 64; ++i, off += 1024) {
    const float kt = (float)k[off];
    const float kv = kt * (float)v[off];
    A = ed * A + kv;
    Bv = ed * Bv + kt;
  }
  scA[gid] = A;
  scB[gid] = Bv;
}

__global__ __launch_bounds__(256) void wkv_scan(const float* __restrict__ td,
    float* __restrict__ scA, float* __restrict__ scB) {
  const int gid = blockIdx.x * 256 + threadIdx.x;   // 8192 = b*1024 + c
  const int c = gid & 1023;
  const int b = gid >> 10;
  const float edL = expf(-expf(td[c]) * 64.0f);     // ed^64
  float a = 0.f, bb = 0.f;
  size_t off = ((size_t)b << 15) + c;
  for (int j = 0; j < 32; ++j, off += 1024) {
    const float Aj = scA[off], Bj = scB[off];
    scA[off] = a;            // carry INTO chunk j
    scB[off] = bb;
    a = edL * a + Aj;
    bb = edL * bb + Bj;
  }
}

__global__ __launch_bounds__(256) void wkv_apply(const __bf16* __restrict__ k,
    const __bf16* __restrict__ v, const __bf16* __restrict__ sr,
    const float* __restrict__ td, const float* __restrict__ tf,
    const float* __restrict__ scA, const float* __restrict__ scB,
    __bf16* __restrict__ srw) {
  const int gid = blockIdx.x * 256 + threadIdx.x;
  const int c = gid & 1023;
  const int j = (gid >> 10) & 31;
  const int b = gid >> 15;
  const float ed = expf(-expf(td[c]));
  const float eu = expf(tf[c]);
  float a = scA[gid], bb = scB[gid];
  size_t off = ((size_t)(b * 2048 + j * 64) << 10) + c;
#pragma unroll 4
  for (int i = 0; i < 64; ++i, off += 1024) {
    const float kt = (float)k[off];
    const float vt = (float)v[off];
    const float kv = kt * vt;
    const float y = (a + eu * kv) / (bb + eu * kt);
    srw[off] = (__bf16)((float)sr[off] * y);
    a = ed * a + kv;
    bb = ed * bb + kt;
  }
}

// ---------------- 256x256 ring-4 deep-pipelined bf16 GEMM ----------------
// out[m,n] = sum_k A[m,k]*W[n,k].  8 waves (2Mx4N), BK=32, ring of 4 LDS slots
// (128 KiB) -> prefetch distance 3 tiles (~930 cyc >= HBM latency).  ONE raw
// barrier + ONE counted vmcnt per tile (steady vmcnt(8), tail 8->4->0).
// 12 ds_read_b128 up front, two 16-MFMA clusters with all-distinct acc
// (dep-free); compiler inserts fine-grained lgkmcnt between reads and uses.
// Both-sides XOR swizzle (uniform 2-way banks = free), setprio, XCD swizzle.
enum { EPI_NONE = 0, EPI_EXP, EPI_SIG, EPI_RELU2, EPI_RESID, EPI_FINAL, EPI_KVR };

#define SBAR() { __builtin_amdgcn_s_barrier(); __builtin_amdgcn_sched_barrier(0); }
#define VMW(n) { asm volatile("s_waitcnt vmcnt(" #n ")" ::: "memory"); __builtin_amdgcn_sched_barrier(0); }

template <int EPI>
__global__ __launch_bounds__(512, 2) void gemmr4(
    const __bf16* __restrict__ A, const __bf16* __restrict__ W,
    void* outp, const void* res, const void* sig, const int N, const int K) {
  __shared__ __bf16 sA[4][8192];   // [slot][256 rows][32 cols], row = 64 B
  __shared__ __bf16 sB[4][8192];
  const int tid = threadIdx.x;
  const int w = tid >> 6, l = tid & 63;
  const int wm = w >> 2, wn = w & 3;

  // bijective XCD swizzle (all grids have nwg % 8 == 0)
  const int nwg = gridDim.x * gridDim.y;
  int wg = blockIdx.y * gridDim.x + blockIdx.x;
  wg = (wg & 7) * (nwg >> 3) + (wg >> 3);
  const int m0 = (wg / gridDim.x) << 8;
  const int n0 = (wg % gridDim.x) << 8;

  // ---- staging (global -> LDS, linear dest, pre-swizzled source) ----
  // lane l: local row = w*16 + (l>>2) (+128*i), dest chunk = l&3 (16B units);
  // source chunk = (l&3) ^ f(row), f(r) = (r&3)^((r>>2)&3) = ((l>>2)&3)^(l>>4)
  const int srcsw = (l & 3) ^ ((l >> 2) & 3) ^ (l >> 4);
  const size_t gA = (size_t)(m0 + w * 16 + (l >> 2)) * K + srcsw * 8;
  const size_t gB = (size_t)(n0 + w * 16 + (l >> 2)) * K + srcsw * 8;
  const int ldsD = w * 512;   // (w*16 rows)*32

  const int NTK = K >> 5;

#define STG_A(kt, i) glds16(A + gA + (size_t)(i) * 128 * K + (size_t)(kt) * 32, &sA[(kt) & 3][(i) * 4096 + ldsD])
#define STG_B(kt, i) glds16(W + gB + (size_t)(i) * 128 * K + (size_t)(kt) * 32, &sB[(kt) & 3][(i) * 4096 + ldsD])

  // ---- fragment reads: row = base + (l&15), want global chunk k0 = l>>4;
  // read LDS chunk = k0 ^ f(row) = (l>>4)^(l&3)^((l>>2)&3)  (lane-constant)
  const int rA = (wm * 128 + (l & 15)) * 32;
  const int rB = (wn * 64 + (l & 15)) * 32;
  const int rdsw = ((l >> 4) ^ (l & 3) ^ ((l >> 2) & 3)) << 3;
#define LDA(s, mi) (*(const bf16x8*)&sA[s][rA + (mi) * 512 + rdsw])
#define LDB(s, ni) (*(const bf16x8*)&sB[s][rB + (ni) * 512 + rdsw])

  f32x4 acc[8][4] = {};

  // prologue: stage tiles 0,1,2 (12 glds, 4 per tile in FIFO groups)
#pragma unroll
  for (int t = 0; t < 3; ++t) { STG_A(t, 0); STG_A(t, 1); STG_B(t, 0); STG_B(t, 1); }

  for (int kt = 0; kt < NTK; ++kt) {
    const int s = kt & 3;
    const int rem = NTK - 1 - kt;    // future tiles whose loads may be in flight
    if (rem >= 2)      { VMW(8); }   // keep tiles kt+1, kt+2 in flight
    else if (rem == 1) { VMW(4); }
    else               { VMW(0); }
    SBAR();                          // all waves' tile-kt data now in LDS
    if (kt + 3 < NTK) { STG_A(kt + 3, 0); STG_A(kt + 3, 1); STG_B(kt + 3, 0); STG_B(kt + 3, 1); }
    bf16x8 av[4], av2[4], bv[4];
#pragma unroll
    for (int i = 0; i < 4; ++i) av[i]  = LDA(s, i);
#pragma unroll
    for (int i = 0; i < 4; ++i) bv[i]  = LDB(s, i);
#pragma unroll
    for (int i = 0; i < 4; ++i) av2[i] = LDA(s, i + 4);
    __builtin_amdgcn_s_setprio(1);
#pragma unroll
    for (int mi = 0; mi < 4; ++mi)
#pragma unroll
      for (int ni = 0; ni < 4; ++ni)
        acc[mi][ni] = __builtin_amdgcn_mfma_f32_16x16x32_bf16(av[mi], bv[ni], acc[mi][ni], 0, 0, 0);
#pragma unroll
    for (int mi = 0; mi < 4; ++mi)
#pragma unroll
      for (int ni = 0; ni < 4; ++ni)
        acc[mi + 4][ni] = __builtin_amdgcn_mfma_f32_16x16x32_bf16(av2[mi], bv[ni], acc[mi + 4][ni], 0, 0, 0);
    __builtin_amdgcn_s_setprio(0);
  }

  // ---- epilogue: C/D map col=lane&15, row=(lane>>4)*4+reg ----
  const int rl = (l >> 4) << 2, cl = l & 15;
#pragma unroll
  for (int mi = 0; mi < 8; ++mi) {
#pragma unroll
    for (int ni = 0; ni < 4; ++ni) {
#pragma unroll
      for (int e = 0; e < 4; ++e) {
        const int r = m0 + (wm << 7) + mi * 16 + rl + e;
        const int cidx = n0 + (wn << 6) + ni * 16 + cl;
        const size_t idx = (size_t)r * N + cidx;
        const float vacc = acc[mi][ni][e];
        if constexpr (EPI == EPI_NONE) {
          ((__bf16*)outp)[idx] = (__bf16)vacc;
        } else if constexpr (EPI == EPI_EXP) {
          ((__bf16*)outp)[idx] = (__bf16)expf(fminf(vacc, 60.0f));
        } else if constexpr (EPI == EPI_SIG) {
          ((__bf16*)outp)[idx] = (__bf16)(1.0f / (1.0f + expf(-vacc)));
        } else if constexpr (EPI == EPI_RELU2) {
          const float rv = fmaxf(vacc, 0.0f);
          ((__bf16*)outp)[idx] = (__bf16)(rv * rv);
        } else if constexpr (EPI == EPI_RESID) {
          ((__bf16*)outp)[idx] = (__bf16)(vacc + (float)((const __bf16*)res)[idx]);
        } else if constexpr (EPI == EPI_FINAL) {
          ((float*)outp)[idx] = ((const float*)res)[idx] + (float)((const __bf16*)sig)[idx] * vacc;
        } else {  // EPI_KVR: col block 0 -> k=exp(clamp), 1 -> v, 2 -> sigmoid(r)
          const int sel = cidx >> 10;               // wave-uniform (16-aligned blocks)
          const size_t oidx = (size_t)r * 1024 + (cidx & 1023);
          if (sel == 0)      ((__bf16*)outp)[oidx] = (__bf16)expf(fminf(vacc, 60.0f));
          else if (sel == 1) ((__bf16*)const_cast<void*>(res))[oidx] = (__bf16)vacc;
          else               ((__bf16*)const_cast<void*>(sig))[oidx] = (__bf16)(1.0f / (1.0f + expf(-vacc)));
        }
      }
    }
  }
}

// ---------------- launch ----------------
extern "C" void kernel_launch(void* const* d_in, const int* in_sizes, int n_in,
                              void* d_out, int out_size, void* d_ws, size_t ws_size,
                              hipStream_t stream) {
  (void)in_sizes; (void)n_in; (void)out_size;
  const float* x    = (const float*)d_in[0];
  const float* ln1g = (const float*)d_in[1];
  const float* ln1b = (const float*)d_in[2];
  const float* ln2g = (const float*)d_in[3];
  const float* ln2b = (const float*)d_in[4];
  const float* atm  = (const float*)d_in[5];
  const float* acm  = (const float*)d_in[6];
  const float* td   = (const float*)d_in[7];
  const float* tf   = (const float*)d_in[8];
  const float* Wk   = (const float*)d_in[9];
  const float* Wv   = (const float*)d_in[10];
  const float* Wr   = (const float*)d_in[11];
  const float* Wo   = (const float*)d_in[12];
  const float* ftm  = (const float*)d_in[13];
  const float* fcm  = (const float*)d_in[14];
  const float* Fk   = (const float*)d_in[15];
  const float* Fv   = (const float*)d_in[16];
  const float* Fr   = (const float*)d_in[17];

  constexpr size_t C = 1024, T = 2048, Bs = 8, H = 4096;
  constexpr size_t NT = Bs * T;        // 16384 tokens
  constexpr size_t NTC = NT * C;       // 16M elems
  constexpr size_t CC = C * C;
  constexpr size_t CH = C * H;

  // ---- workspace layout ----
  char* p = (char*)d_ws;
  auto takeb = [&](size_t elems) { __bf16* q = (__bf16*)p; p += elems * 2; return q; };
  __bf16* wKVR = takeb(3 * CC);   // [Wk; Wv; Wr] rows stacked -> (3072, 1024)
  __bf16* wWo  = takeb(CC);
  __bf16* wFk  = takeb(CH);
  __bf16* wFv  = takeb(CH);
  __bf16* wFr  = takeb(CC);
  __bf16* Ab   = takeb(NTC);      // x1 -> x2 (in-place residual)
  __bf16* Bb   = takeb(NTC);      // xm -> srw -> sr2
  __bf16* Db   = takeb(NTC);      // v  -> xm2
  float* scA = (float*)p; p += Bs * 32 * C * 4;   // wkv carries (b,j,c)
  float* scB = (float*)p; p += Bs * 32 * C * 4;
  __bf16* kk = (__bf16*)p;        // k lives here too (dead before Fk writes kk)
  const size_t used = (size_t)(p - (char*)d_ws);
  const size_t kkcap = ws_size > used ? ws_size - used : 0;
  int chunks = 4;                                   // 32 MiB kk
  if (kkcap >= NT * H * 2)          chunks = 1;     // 128 MiB kk
  else if (kkcap >= NT * H)         chunks = 2;     // 64 MiB kk
  __bf16* Cb = kk;                 // k buffer (32 MiB) aliases kk region
  __bf16* sr  = (__bf16*)d_out;    // sigmoid(r) borrows d_out until ln2 overwrites it
  float*  x3  = (float*)d_out;

  auto cvt = [&](const float* src, size_t n, __bf16* dst) {
    const int n4 = (int)(n / 4);
    cvt_bf16<<<dim3((n4 + 255) / 256), dim3(256), 0, stream>>>(src, dst, n4);
  };
  cvt(Wk, CC, wKVR); cvt(Wv, CC, wKVR + CC); cvt(Wr, CC, wKVR + 2 * CC);
  cvt(Wo, CC, wWo); cvt(Fk, CH, wFk); cvt(Fv, CH, wFv); cvt(Fr, CC, wFr);

  const dim3 blk(256), blkG(512);

  // x1 = ln1(x)            [Ab]
  ln_kernel<float, __bf16><<<dim3((unsigned)NT), blk, 0, stream>>>(x, ln1g, ln1b, Ab);
  // xm = mix(x1)           [Bb]
  mix_kernel<__bf16><<<dim3((unsigned)(NTC / 1024)), blk, 0, stream>>>(Ab, atm, acm, Bb);
  // fused: k=exp(min(.,60)) [Cb], v [Db], sigmoid(r) [sr]
  gemmr4<EPI_KVR><<<dim3(12, 64), blkG, 0, stream>>>(Bb, wKVR, Cb, Db, sr, 3072, 1024);
  // wkv: chunk partials -> carry scan -> apply (srw = sigmoid(r)*y into Bb)
  wkv_part<<<dim3(1024), blk, 0, stream>>>(Cb, Db, td, scA, scB);
  wkv_scan<<<dim3(32), blk, 0, stream>>>(td, scA, scB);
  wkv_apply<<<dim3(1024), blk, 0, stream>>>(Cb, Db, sr, td, tf, scA, scB, Bb);
  // x2 = x1 + srw@Wo^T     [Ab in-place]
  gemmr4<EPI_RESID><<<dim3(4, 64), blkG, 0, stream>>>(Bb, wWo, Ab, Ab, nullptr, 1024, 1024);
  // x3 = ln2(x2)           [d_out, fp32]
  ln_kernel<__bf16, float><<<dim3((unsigned)NT), blk, 0, stream>>>(Ab, ln2g, ln2b, x3);
  // xm2 = mix(x3)          [Db]
  mix_kernel<float><<<dim3((unsigned)(NTC / 1024)), blk, 0, stream>>>(x3, ftm, fcm, Db);
  // sr2 = sigmoid(xm2@Fr^T) [Bb]
  gemmr4<EPI_SIG><<<dim3(4, 64), blkG, 0, stream>>>(Db, wFr, Bb, nullptr, nullptr, 1024, 1024);
  // FFN: kk = relu(xm2@Fk^T)^2 [kk], out = x3 + sr2 * (kk@Fv^T)  (chunked if ws small)
  const size_t Mc = NT / chunks;
  for (int ch = 0; ch < chunks; ++ch) {
    const size_t ro = (size_t)ch * Mc;
    gemmr4<EPI_RELU2><<<dim3(16, (unsigned)(Mc / 256)), blkG, 0, stream>>>(
        Db + ro * C, wFk, kk, nullptr, nullptr, 4096, 1024);
    gemmr4<EPI_FINAL><<<dim3(4, (unsigned)(Mc / 256)), blkG, 0, stream>>>(
        kk, wFv, (float*)d_out + ro * C, (const float*)d_out + ro * C,
        Bb + ro * C, 1024, 4096);
  }
}

// Round 9
// 777.517 us; speedup vs baseline: 1.1308x; 1.1308x over previous
//
#include <hip/hip_runtime.h>
#include <hip/hip_bf16.h>

typedef float f32x4 __attribute__((ext_vector_type(4)));
typedef __bf16 bf16x8 __attribute__((ext_vector_type(8)));
typedef __bf16 bf16x4 __attribute__((ext_vector_type(4)));

#define DEVI static __device__ __forceinline__

DEVI void glds16(const void* g, void* l) {
  __builtin_amdgcn_global_load_lds((__attribute__((address_space(1))) void*)g,
                                   (__attribute__((address_space(3))) void*)l, 16, 0, 0);
}

DEVI f32x4 load4(const float* p) { return *(const f32x4*)p; }
DEVI f32x4 load4(const __bf16* p) {
  bf16x4 v = *(const bf16x4*)p;
  f32x4 o = { (float)v[0], (float)v[1], (float)v[2], (float)v[3] };
  return o;
}
DEVI void store4(float* p, f32x4 v) { *(f32x4*)p = v; }
DEVI void store4(__bf16* p, f32x4 v) {
  bf16x4 o = { (__bf16)v[0], (__bf16)v[1], (__bf16)v[2], (__bf16)v[3] };
  *(bf16x4*)p = o;
}

// ---------------- weight fp32 -> bf16 ----------------
__global__ void cvt_bf16(const float* __restrict__ in, __bf16* __restrict__ out, int n4) {
  int i = blockIdx.x * 256 + threadIdx.x;
  if (i < n4) {
    f32x4 v = *(const f32x4*)(in + (size_t)i * 4);
    store4(out + (size_t)i * 4, v);
  }
}

// ---------------- LayerNorm over C=1024, one block per token ----------------
template <typename TIN, typename TOUT>
__global__ __launch_bounds__(256) void ln_kernel(const TIN* __restrict__ x,
    const float* __restrict__ gw, const float* __restrict__ bw,
    TOUT* __restrict__ out) {
  const size_t row = blockIdx.x;
  f32x4 v = load4(x + row * 1024 + threadIdx.x * 4);
  float s = v[0] + v[1] + v[2] + v[3];
  float q = v[0]*v[0] + v[1]*v[1] + v[2]*v[2] + v[3]*v[3];
#pragma unroll
  for (int o = 32; o > 0; o >>= 1) { s += __shfl_down(s, o); q += __shfl_down(q, o); }
  __shared__ float ss[4], qq[4];
  const int w = threadIdx.x >> 6, l = threadIdx.x & 63;
  if (l == 0) { ss[w] = s; qq[w] = q; }
  __syncthreads();
  s = ss[0] + ss[1] + ss[2] + ss[3];
  q = qq[0] + qq[1] + qq[2] + qq[3];
  const float mean = s * (1.0f / 1024.0f);
  const float var = q * (1.0f / 1024.0f) - mean * mean;
  const float rstd = rsqrtf(var + 1e-5f);
  f32x4 g4 = *(const f32x4*)(gw + threadIdx.x * 4);
  f32x4 b4 = *(const f32x4*)(bw + threadIdx.x * 4);
  f32x4 o;
#pragma unroll
  for (int j = 0; j < 4; ++j) o[j] = (v[j] - mean) * rstd * g4[j] + b4[j];
  store4(out + row * 1024 + threadIdx.x * 4, o);
}

// ---------------- time-shift mix -> bf16 ----------------
template <typename TIN>
__global__ __launch_bounds__(256) void mix_kernel(const TIN* __restrict__ x,
    const float* __restrict__ tm, const float* __restrict__ cm,
    __bf16* __restrict__ out) {
  const int idx = blockIdx.x * 256 + threadIdx.x;   // over B*T*C/4
  const int t = (idx >> 8) & 2047;                   // T=2048
  const int c = (idx & 255) * 4;                     // C/4=256
  const size_t base = ((size_t)(idx >> 8) << 10) + c;
  f32x4 xv = load4(x + base);
  f32x4 xm1 = {0.f, 0.f, 0.f, 0.f}, xp1 = {0.f, 0.f, 0.f, 0.f};
  if (t > 0)    xm1 = load4(x + base - 1024);
  if (t < 2047) xp1 = load4(x + base + 1024);
  f32x4 tm4 = *(const f32x4*)(tm + c);
  f32x4 cm4 = *(const f32x4*)(cm + c);
  f32x4 xc = (c < 512) ? xm1 : xp1;
  f32x4 o;
#pragma unroll
  for (int j = 0; j < 4; ++j)
    o[j] = xv[j] * tm4[j] + xm1[j] * (1.0f - tm4[j]) + xc[j] * cm4[j];
  store4(out + base, o);
}

// ---------------- WKV chunk-parallel scan (exact regroup of reference) ----------------
__global__ __launch_bounds__(256) void wkv_part(const __bf16* __restrict__ k,
    const __bf16* __restrict__ v, const float* __restrict__ td,
    float* __restrict__ scA, float* __restrict__ scB) {
  const int gid = blockIdx.x * 256 + threadIdx.x;   // b*32768 + j*1024 + c
  const int c = gid & 1023;
  const int j = (gid >> 10) & 31;
  const int b = gid >> 15;
  const float ed = expf(-expf(td[c]));
  float A = 0.f, Bv = 0.f;
  size_t off = ((size_t)(b * 2048 + j * 64) << 10) + c;
#pragma unroll 4
  for (int i = 0; i < 64; ++i, off += 1024) {
    const float kt = (float)k[off];
    const float kv = kt * (float)v[off];
    A = ed * A + kv;
    Bv = ed * Bv + kt;
  }
  scA[gid] = A;
  scB[gid] = Bv;
}

__global__ __launch_bounds__(256) void wkv_scan(const float* __restrict__ td,
    float* __restrict__ scA, float* __restrict__ scB) {
  const int gid = blockIdx.x * 256 + threadIdx.x;   // 8192 = b*1024 + c
  const int c = gid & 1023;
  const int b = gid >> 10;
  const float edL = expf(-expf(td[c]) * 64.0f);     // ed^64
  float a = 0.f, bb = 0.f;
  size_t off = ((size_t)b << 15) + c;
  for (int j = 0; j < 32; ++j, off += 1024) {
    const float Aj = scA[off], Bj = scB[off];
    scA[off] = a;            // carry INTO chunk j
    scB[off] = bb;
    a = edL * a + Aj;
    bb = edL * bb + Bj;
  }
}

__global__ __launch_bounds__(256) void wkv_apply(const __bf16* __restrict__ k,
    const __bf16* __restrict__ v, const __bf16* __restrict__ sr,
    const float* __restrict__ td, const float* __restrict__ tf,
    const float* __restrict__ scA, const float* __restrict__ scB,
    __bf16* __restrict__ srw) {
  const int gid = blockIdx.x * 256 + threadIdx.x;
  const int c = gid & 1023;
  const int j = (gid >> 10) & 31;
  const int b = gid >> 15;
  const float ed = expf(-expf(td[c]));
  const float eu = expf(tf[c]);
  float a = scA[gid], bb = scB[gid];
  size_t off = ((size_t)(b * 2048 + j * 64) << 10) + c;
#pragma unroll 4
  for (int i = 0; i < 64; ++i, off += 1024) {
    const float kt = (float)k[off];
    const float vt = (float)v[off];
    const float kv = kt * vt;
    const float y = (a + eu * kv) / (bb + eu * kt);
    srw[off] = (__bf16)((float)sr[off] * y);
    a = ed * a + kv;
    bb = ed * bb + kt;
  }
}

// ---------------- 256x256 software-pipelined bf16 GEMM ----------------
// out[m,n] = sum_k A[m,k]*W[n,k].  8 waves (2Mx4N), BK=64, dbuf LDS (128 KiB,
// 128-B rows -- the verified 0-conflict layout from R5).  ONE vmcnt(0) + ONE
// barrier per K-tile; 8 stage-glds issued right after the barrier (1-tile
// prefetch lead).  ds_reads grouped + pinned (sched_barrier); MFMA clusters
// gated by COUNTED lgkmcnt(4/8/4/0) so reads retire under the previous
// cluster's MFMAs.  Both-sides XOR swizzle, setprio, bijective XCD swizzle.
enum { EPI_NONE = 0, EPI_EXP, EPI_SIG, EPI_RELU2, EPI_RESID, EPI_FINAL, EPI_KVR };

#define SCHED0() __builtin_amdgcn_sched_barrier(0)
#define SBAR() { __builtin_amdgcn_s_barrier(); SCHED0(); }
#define VMW0() { asm volatile("s_waitcnt vmcnt(0)" ::: "memory"); SCHED0(); }
#define LGKM(n) { asm volatile("s_waitcnt lgkmcnt(" #n ")" ::: "memory"); SCHED0(); }

template <int EPI>
__global__ __launch_bounds__(512, 2) void gemmk(
    const __bf16* __restrict__ A, const __bf16* __restrict__ W,
    void* outp, const void* res, const void* sig, const int N, const int K) {
  __shared__ __bf16 sA[2][16384];   // [buf][256 rows][64 cols], row = 128 B
  __shared__ __bf16 sB[2][16384];
  const int tid = threadIdx.x;
  const int w = tid >> 6, l = tid & 63;
  const int wm = w >> 2, wn = w & 3;

  // bijective XCD swizzle (all grids have nwg % 8 == 0)
  const int nwg = gridDim.x * gridDim.y;
  int wg = blockIdx.y * gridDim.x + blockIdx.x;
  wg = (wg & 7) * (nwg >> 3) + (wg >> 3);
  const int m0 = (wg / gridDim.x) << 8;
  const int n0 = (wg % gridDim.x) << 8;

  // ---- staging (global -> LDS, linear dest, pre-swizzled source) ----
  // lane l: LDS row = base + (l>>3), chunk = l&7; source chunk = (l&7)^(l>>3)
  const int lr = l >> 3;
  const int lc = (l & 7) ^ lr;
  const size_t gA = (size_t)(m0 + w * 8 + lr) * K + lc * 8;            // A issue i: +i*64 rows
  const size_t gB = (size_t)(n0 + wn * 64 + wm * 8 + lr) * K + lc * 8; // B issue j: +j*16 rows
  const int ldsA = w * 512;                  // (w*8 rows)*64
  const int ldsB = (wn * 64 + wm * 8) * 64;

  const int NTK = K >> 6;

#define STAGE_A(buf, kt, i) glds16(A + gA + (size_t)(i) * 64 * K + (size_t)(kt) * 64, &sA[buf][ldsA + (i) * 4096])
#define STAGE_B(buf, kt, j) glds16(W + gB + (size_t)(j) * 16 * K + (size_t)(kt) * 64, &sB[buf][ldsB + (j) * 1024])

  // ---- fragment reads (swizzled chunk) ----
  const int rA = (wm * 128 + (l & 15)) * 64;
  const int rB = (wn * 64 + (l & 15)) * 64;
  const int csw = l & 7;
  const int k0 = l >> 4;    // 0..3
#define LDA(buf, mi, kk) (*(const bf16x8*)&sA[buf][rA + (mi) * 1024 + ((((kk) * 4 + k0) ^ csw) << 3)])
#define LDB(buf, ni, kk) (*(const bf16x8*)&sB[buf][rB + (ni) * 1024 + ((((kk) * 4 + k0) ^ csw) << 3)])

  f32x4 acc[8][4] = {};

  // prologue: stage tile 0 into buf 0
  STAGE_A(0, 0, 0); STAGE_A(0, 0, 1); STAGE_A(0, 0, 2); STAGE_A(0, 0, 3);
  STAGE_B(0, 0, 0); STAGE_B(0, 0, 1); STAGE_B(0, 0, 2); STAGE_B(0, 0, 3);

  for (int kt = 0; kt < NTK; ++kt) {
    const int buf = kt & 1, nb = buf ^ 1;
    const bool st = (kt + 1 < NTK);
    VMW0();                     // tile-kt staging landed
    SBAR();                     // everyone done reading buf nb (tile kt-1)
    if (st) {                   // stage tile kt+1 (issues overlap whole tile)
      STAGE_A(nb, kt + 1, 0); STAGE_A(nb, kt + 1, 1); STAGE_A(nb, kt + 1, 2); STAGE_A(nb, kt + 1, 3);
      STAGE_B(nb, kt + 1, 0); STAGE_B(nb, kt + 1, 1); STAGE_B(nb, kt + 1, 2); STAGE_B(nb, kt + 1, 3);
    }
    SCHED0();
    bf16x8 a0[4], a1[4], a2[4], a3[4], b0[4], b1[4];
    // R1: 8 reads (cluster-1 operands)
#pragma unroll
    for (int i = 0; i < 4; ++i) a0[i] = LDA(buf, i, 0);
#pragma unroll
    for (int i = 0; i < 4; ++i) b0[i] = LDB(buf, i, 0);
    SCHED0();
    // R2: 4 reads (cluster-2 A)
#pragma unroll
    for (int i = 0; i < 4; ++i) a1[i] = LDA(buf, i + 4, 0);
    SCHED0();
    LGKM(4);                    // R1 retired (R2 may fly)
    __builtin_amdgcn_s_setprio(1);
#pragma unroll
    for (int mi = 0; mi < 4; ++mi)
#pragma unroll
      for (int ni = 0; ni < 4; ++ni)
        acc[mi][ni] = __builtin_amdgcn_mfma_f32_16x16x32_bf16(a0[mi], b0[ni], acc[mi][ni], 0, 0, 0);
    __builtin_amdgcn_s_setprio(0); SCHED0();
    // R3: 8 reads (cluster-3 operands)
#pragma unroll
    for (int i = 0; i < 4; ++i) a2[i] = LDA(buf, i, 1);
#pragma unroll
    for (int i = 0; i < 4; ++i) b1[i] = LDB(buf, i, 1);
    SCHED0();
    LGKM(8);                    // R2 retired (R3 may fly)
    __builtin_amdgcn_s_setprio(1);
#pragma unroll
    for (int mi = 0; mi < 4; ++mi)
#pragma unroll
      for (int ni = 0; ni < 4; ++ni)
        acc[mi + 4][ni] = __builtin_amdgcn_mfma_f32_16x16x32_bf16(a1[mi], b0[ni], acc[mi + 4][ni], 0, 0, 0);
    __builtin_amdgcn_s_setprio(0); SCHED0();
    // R4: 4 reads (cluster-4 A)
#pragma unroll
    for (int i = 0; i < 4; ++i) a3[i] = LDA(buf, i + 4, 1);
    SCHED0();
    LGKM(4);                    // R3 retired (R4 may fly)
    __builtin_amdgcn_s_setprio(1);
#pragma unroll
    for (int mi = 0; mi < 4; ++mi)
#pragma unroll
      for (int ni = 0; ni < 4; ++ni)
        acc[mi][ni] = __builtin_amdgcn_mfma_f32_16x16x32_bf16(a2[mi], b1[ni], acc[mi][ni], 0, 0, 0);
    __builtin_amdgcn_s_setprio(0); SCHED0();
    LGKM(0);                    // R4 retired
    __builtin_amdgcn_s_setprio(1);
#pragma unroll
    for (int mi = 0; mi < 4; ++mi)
#pragma unroll
      for (int ni = 0; ni < 4; ++ni)
        acc[mi + 4][ni] = __builtin_amdgcn_mfma_f32_16x16x32_bf16(a3[mi], b1[ni], acc[mi + 4][ni], 0, 0, 0);
    __builtin_amdgcn_s_setprio(0);
  }

  // ---- epilogue: C/D map col=lane&15, row=(lane>>4)*4+reg ----
  const int rl = (l >> 4) << 2, cl = l & 15;
#pragma unroll
  for (int mi = 0; mi < 8; ++mi) {
#pragma unroll
    for (int ni = 0; ni < 4; ++ni) {
#pragma unroll
      for (int e = 0; e < 4; ++e) {
        const int r = m0 + (wm << 7) + mi * 16 + rl + e;
        const int cidx = n0 + (wn << 6) + ni * 16 + cl;
        const size_t idx = (size_t)r * N + cidx;
        const float vacc = acc[mi][ni][e];
        if constexpr (EPI == EPI_NONE) {
          ((__bf16*)outp)[idx] = (__bf16)vacc;
        } else if constexpr (EPI == EPI_EXP) {
          ((__bf16*)outp)[idx] = (__bf16)expf(fminf(vacc, 60.0f));
        } else if constexpr (EPI == EPI_SIG) {
          ((__bf16*)outp)[idx] = (__bf16)(1.0f / (1.0f + expf(-vacc)));
        } else if constexpr (EPI == EPI_RELU2) {
          const float rv = fmaxf(vacc, 0.0f);
          ((__bf16*)outp)[idx] = (__bf16)(rv * rv);
        } else if constexpr (EPI == EPI_RESID) {
          ((__bf16*)outp)[idx] = (__bf16)(vacc + (float)((const __bf16*)res)[idx]);
        } else if constexpr (EPI == EPI_FINAL) {
          ((float*)outp)[idx] = ((const float*)res)[idx] + (float)((const __bf16*)sig)[idx] * vacc;
        } else {  // EPI_KVR: col block 0 -> k=exp(clamp), 1 -> v, 2 -> sigmoid(r)
          const int sel = cidx >> 10;               // wave-uniform (16-aligned blocks)
          const size_t oidx = (size_t)r * 1024 + (cidx & 1023);
          if (sel == 0)      ((__bf16*)outp)[oidx] = (__bf16)expf(fminf(vacc, 60.0f));
          else if (sel == 1) ((__bf16*)const_cast<void*>(res))[oidx] = (__bf16)vacc;
          else               ((__bf16*)const_cast<void*>(sig))[oidx] = (__bf16)(1.0f / (1.0f + expf(-vacc)));
        }
      }
    }
  }
}

// ---------------- launch ----------------
extern "C" void kernel_launch(void* const* d_in, const int* in_sizes, int n_in,
                              void* d_out, int out_size, void* d_ws, size_t ws_size,
                              hipStream_t stream) {
  (void)in_sizes; (void)n_in; (void)out_size;
  const float* x    = (const float*)d_in[0];
  const float* ln1g = (const float*)d_in[1];
  const float* ln1b = (const float*)d_in[2];
  const float* ln2g = (const float*)d_in[3];
  const float* ln2b = (const float*)d_in[4];
  const float* atm  = (const float*)d_in[5];
  const float* acm  = (const float*)d_in[6];
  const float* td   = (const float*)d_in[7];
  const float* tf   = (const float*)d_in[8];
  const float* Wk   = (const float*)d_in[9];
  const float* Wv   = (const float*)d_in[10];
  const float* Wr   = (const float*)d_in[11];
  const float* Wo   = (const float*)d_in[12];
  const float* ftm  = (const float*)d_in[13];
  const float* fcm  = (const float*)d_in[14];
  const float* Fk   = (const float*)d_in[15];
  const float* Fv   = (const float*)d_in[16];
  const float* Fr   = (const float*)d_in[17];

  constexpr size_t C = 1024, T = 2048, Bs = 8, H = 4096;
  constexpr size_t NT = Bs * T;        // 16384 tokens
  constexpr size_t NTC = NT * C;       // 16M elems
  constexpr size_t CC = C * C;
  constexpr size_t CH = C * H;

  // ---- workspace layout ----
  char* p = (char*)d_ws;
  auto takeb = [&](size_t elems) { __bf16* q = (__bf16*)p; p += elems * 2; return q; };
  __bf16* wKVR = takeb(3 * CC);   // [Wk; Wv; Wr] rows stacked -> (3072, 1024)
  __bf16* wWo  = takeb(CC);
  __bf16* wFk  = takeb(CH);
  __bf16* wFv  = takeb(CH);
  __bf16* wFr  = takeb(CC);
  __bf16* Ab   = takeb(NTC);      // x1 -> x2 (in-place residual)
  __bf16* Bb   = takeb(NTC);      // xm -> srw -> sr2
  __bf16* Db   = takeb(NTC);      // v  -> xm2
  float* scA = (float*)p; p += Bs * 32 * C * 4;   // wkv carries (b,j,c)
  float* scB = (float*)p; p += Bs * 32 * C * 4;
  __bf16* kk = (__bf16*)p;        // k lives here too (dead before Fk writes kk)
  const size_t used = (size_t)(p - (char*)d_ws);
  const size_t kkcap = ws_size > used ? ws_size - used : 0;
  int chunks = 4;                                   // 32 MiB kk
  if (kkcap >= NT * H * 2)          chunks = 1;     // 128 MiB kk
  else if (kkcap >= NT * H)         chunks = 2;     // 64 MiB kk
  __bf16* Cb = kk;                 // k buffer (32 MiB) aliases kk region
  __bf16* sr  = (__bf16*)d_out;    // sigmoid(r) borrows d_out until ln2 overwrites it
  float*  x3  = (float*)d_out;

  auto cvt = [&](const float* src, size_t n, __bf16* dst) {
    const int n4 = (int)(n / 4);
    cvt_bf16<<<dim3((n4 + 255) / 256), dim3(256), 0, stream>>>(src, dst, n4);
  };
  cvt(Wk, CC, wKVR); cvt(Wv, CC, wKVR + CC); cvt(Wr, CC, wKVR + 2 * CC);
  cvt(Wo, CC, wWo); cvt(Fk, CH, wFk); cvt(Fv, CH, wFv); cvt(Fr, CC, wFr);

  const dim3 blk(256), blkG(512);

  // x1 = ln1(x)            [Ab]
  ln_kernel<float, __bf16><<<dim3((unsigned)NT), blk, 0, stream>>>(x, ln1g, ln1b, Ab);
  // xm = mix(x1)           [Bb]
  mix_kernel<__bf16><<<dim3((unsigned)(NTC / 1024)), blk, 0, stream>>>(Ab, atm, acm, Bb);
  // fused: k=exp(min(.,60)) [Cb], v [Db], sigmoid(r) [sr]
  gemmk<EPI_KVR><<<dim3(12, 64), blkG, 0, stream>>>(Bb, wKVR, Cb, Db, sr, 3072, 1024);
  // wkv: chunk partials -> carry scan -> apply (srw = sigmoid(r)*y into Bb)
  wkv_part<<<dim3(1024), blk, 0, stream>>>(Cb, Db, td, scA, scB);
  wkv_scan<<<dim3(32), blk, 0, stream>>>(td, scA, scB);
  wkv_apply<<<dim3(1024), blk, 0, stream>>>(Cb, Db, sr, td, tf, scA, scB, Bb);
  // x2 = x1 + srw@Wo^T     [Ab in-place]
  gemmk<EPI_RESID><<<dim3(4, 64), blkG, 0, stream>>>(Bb, wWo, Ab, Ab, nullptr, 1024, 1024);
  // x3 = ln2(x2)           [d_out, fp32]
  ln_kernel<__bf16, float><<<dim3((unsigned)NT), blk, 0, stream>>>(Ab, ln2g, ln2b, x3);
  // xm2 = mix(x3)          [Db]
  mix_kernel<float><<<dim3((unsigned)(NTC / 1024)), blk, 0, stream>>>(x3, ftm, fcm, Db);
  // sr2 = sigmoid(xm2@Fr^T) [Bb]
  gemmk<EPI_SIG><<<dim3(4, 64), blkG, 0, stream>>>(Db, wFr, Bb, nullptr, nullptr, 1024, 1024);
  // FFN: kk = relu(xm2@Fk^T)^2 [kk], out = x3 + sr2 * (kk@Fv^T)  (chunked if ws small)
  const size_t Mc = NT / chunks;
  for (int ch = 0; ch < chunks; ++ch) {
    const size_t ro = (size_t)ch * Mc;
    gemmk<EPI_RELU2><<<dim3(16, (unsigned)(Mc / 256)), blkG, 0, stream>>>(
        Db + ro * C, wFk, kk, nullptr, nullptr, 4096, 1024);
    gemmk<EPI_FINAL><<<dim3(4, (unsigned)(Mc / 256)), blkG, 0, stream>>>(
        kk, wFv, (float*)d_out + ro * C, (const float*)d_out + ro * C,
        Bb + ro * C, 1024, 4096);
  }
}

// Round 10
// 724.609 us; speedup vs baseline: 1.2134x; 1.0730x over previous
//
#include <hip/hip_runtime.h>
#include <hip/hip_bf16.h>

typedef float f32x4 __attribute__((ext_vector_type(4)));
typedef __bf16 bf16x8 __attribute__((ext_vector_type(8)));
typedef __bf16 bf16x4 __attribute__((ext_vector_type(4)));

#define DEVI static __device__ __forceinline__

DEVI void glds16(const void* g, void* l) {
  __builtin_amdgcn_global_load_lds((__attribute__((address_space(1))) void*)g,
                                   (__attribute__((address_space(3))) void*)l, 16, 0, 0);
}

DEVI f32x4 load4(const float* p) { return *(const f32x4*)p; }
DEVI f32x4 load4(const __bf16* p) {
  bf16x4 v = *(const bf16x4*)p;
  f32x4 o = { (float)v[0], (float)v[1], (float)v[2], (float)v[3] };
  return o;
}
DEVI void store4(float* p, f32x4 v) { *(f32x4*)p = v; }
DEVI void store4(__bf16* p, f32x4 v) {
  bf16x4 o = { (__bf16)v[0], (__bf16)v[1], (__bf16)v[2], (__bf16)v[3] };
  *(bf16x4*)p = o;
}

// ---------------- weight fp32 -> bf16 ----------------
__global__ void cvt_bf16(const float* __restrict__ in, __bf16* __restrict__ out, int n4) {
  int i = blockIdx.x * 256 + threadIdx.x;
  if (i < n4) {
    f32x4 v = *(const f32x4*)(in + (size_t)i * 4);
    store4(out + (size_t)i * 4, v);
  }
}

// ---------------- LayerNorm over C=1024, one block per token ----------------
template <typename TIN, typename TOUT>
__global__ __launch_bounds__(256) void ln_kernel(const TIN* __restrict__ x,
    const float* __restrict__ gw, const float* __restrict__ bw,
    TOUT* __restrict__ out) {
  const size_t row = blockIdx.x;
  f32x4 v = load4(x + row * 1024 + threadIdx.x * 4);
  float s = v[0] + v[1] + v[2] + v[3];
  float q = v[0]*v[0] + v[1]*v[1] + v[2]*v[2] + v[3]*v[3];
#pragma unroll
  for (int o = 32; o > 0; o >>= 1) { s += __shfl_down(s, o); q += __shfl_down(q, o); }
  __shared__ float ss[4], qq[4];
  const int w = threadIdx.x >> 6, l = threadIdx.x & 63;
  if (l == 0) { ss[w] = s; qq[w] = q; }
  __syncthreads();
  s = ss[0] + ss[1] + ss[2] + ss[3];
  q = qq[0] + qq[1] + qq[2] + qq[3];
  const float mean = s * (1.0f / 1024.0f);
  const float var = q * (1.0f / 1024.0f) - mean * mean;
  const float rstd = rsqrtf(var + 1e-5f);
  f32x4 g4 = *(const f32x4*)(gw + threadIdx.x * 4);
  f32x4 b4 = *(const f32x4*)(bw + threadIdx.x * 4);
  f32x4 o;
#pragma unroll
  for (int j = 0; j < 4; ++j) o[j] = (v[j] - mean) * rstd * g4[j] + b4[j];
  store4(out + row * 1024 + threadIdx.x * 4, o);
}

// ---------------- time-shift mix -> bf16 ----------------
template <typename TIN>
__global__ __launch_bounds__(256) void mix_kernel(const TIN* __restrict__ x,
    const float* __restrict__ tm, const float* __restrict__ cm,
    __bf16* __restrict__ out) {
  const int idx = blockIdx.x * 256 + threadIdx.x;   // over B*T*C/4
  const int t = (idx >> 8) & 2047;                   // T=2048
  const int c = (idx & 255) * 4;                     // C/4=256
  const size_t base = ((size_t)(idx >> 8) << 10) + c;
  f32x4 xv = load4(x + base);
  f32x4 xm1 = {0.f, 0.f, 0.f, 0.f}, xp1 = {0.f, 0.f, 0.f, 0.f};
  if (t > 0)    xm1 = load4(x + base - 1024);
  if (t < 2047) xp1 = load4(x + base + 1024);
  f32x4 tm4 = *(const f32x4*)(tm + c);
  f32x4 cm4 = *(const f32x4*)(cm + c);
  f32x4 xc = (c < 512) ? xm1 : xp1;
  f32x4 o;
#pragma unroll
  for (int j = 0; j < 4; ++j)
    o[j] = xv[j] * tm4[j] + xm1[j] * (1.0f - tm4[j]) + xc[j] * cm4[j];
  store4(out + base, o);
}

// ---------------- WKV chunk-parallel scan (exact regroup of reference) ----------------
__global__ __launch_bounds__(256) void wkv_part(const __bf16* __restrict__ k,
    const __bf16* __restrict__ v, const float* __restrict__ td,
    float* __restrict__ scA, float* __restrict__ scB) {
  const int gid = blockIdx.x * 256 + threadIdx.x;   // b*32768 + j*1024 + c
  const int c = gid & 1023;
  const int j = (gid >> 10) & 31;
  const int b = gid >> 15;
  const float ed = expf(-expf(td[c]));
  float A = 0.f, Bv = 0.f;
  size_t off = ((size_t)(b * 2048 + j * 64) << 10) + c;
#pragma unroll 4
  for (int i = 0; i < 64; ++i, off += 1024) {
    const float kt = (float)k[off];
    const float kv = kt * (float)v[off];
    A = ed * A + kv;
    Bv = ed * Bv + kt;
  }
  scA[gid] = A;
  scB[gid] = Bv;
}

__global__ __launch_bounds__(256) void wkv_scan(const float* __restrict__ td,
    float* __restrict__ scA, float* __restrict__ scB) {
  const int gid = blockIdx.x * 256 + threadIdx.x;   // 8192 = b*1024 + c
  const int c = gid & 1023;
  const int b = gid >> 10;
  const float edL = expf(-expf(td[c]) * 64.0f);     // ed^64
  float a = 0.f, bb = 0.f;
  size_t off = ((size_t)b << 15) + c;
  for (int j = 0; j < 32; ++j, off += 1024) {
    const float Aj = scA[off], Bj = scB[off];
    scA[off] = a;            // carry INTO chunk j
    scB[off] = bb;
    a = edL * a + Aj;
    bb = edL * bb + Bj;
  }
}

__global__ __launch_bounds__(256) void wkv_apply(const __bf16* __restrict__ k,
    const __bf16* __restrict__ v, const __bf16* __restrict__ sr,
    const float* __restrict__ td, const float* __restrict__ tf,
    const float* __restrict__ scA, const float* __restrict__ scB,
    __bf16* __restrict__ srw) {
  const int gid = blockIdx.x * 256 + threadIdx.x;
  const int c = gid & 1023;
  const int j = (gid >> 10) & 31;
  const int b = gid >> 15;
  const float ed = expf(-expf(td[c]));
  const float eu = expf(tf[c]);
  float a = scA[gid], bb = scB[gid];
  size_t off = ((size_t)(b * 2048 + j * 64) << 10) + c;
#pragma unroll 4
  for (int i = 0; i < 64; ++i, off += 1024) {
    const float kt = (float)k[off];
    const float vt = (float)v[off];
    const float kv = kt * vt;
    const float y = (a + eu * kv) / (bb + eu * kt);
    srw[off] = (__bf16)((float)sr[off] * y);
    a = ed * a + kv;
    bb = ed * bb + kt;
  }
}

// ---------------- 256x256 m201-pattern bf16 GEMM ----------------
// out[m,n] = sum_k A[m,k]*W[n,k].  8 waves (2Mx4N), BK=64, dbuf LDS (128 KiB,
// 128-B rows, 0-conflict XOR swizzle).  Per K-tile: 4 phases, each
// {ds_reads -> 2 stage-glds -> SBAR -> lgkm(0) -> setprio + 16 indep MFMAs}.
// KEY (m201): reads issued BEFORE the barrier, lgkm(0) AFTER -- barrier
// rendezvous absorbs DS latency.  Counted VMW(2) at end-P0 / end-P3 only
// (FIFO ledger; never 0 in steady state; tail peels).  XCD swizzle.
enum { EPI_NONE = 0, EPI_EXP, EPI_SIG, EPI_RELU2, EPI_RESID, EPI_FINAL, EPI_KVR };

#define SCHED0() __builtin_amdgcn_sched_barrier(0)
#define SBAR() { __builtin_amdgcn_s_barrier(); SCHED0(); }
#define VMW(n) { asm volatile("s_waitcnt vmcnt(" #n ")" ::: "memory"); SCHED0(); }
#define LGKM0() { asm volatile("s_waitcnt lgkmcnt(0)" ::: "memory"); SCHED0(); }

template <int EPI>
__global__ __launch_bounds__(512, 2) void gemmk(
    const __bf16* __restrict__ A, const __bf16* __restrict__ W,
    void* outp, const void* res, const void* sig, const int N, const int K) {
  __shared__ __bf16 sA[2][16384];   // [buf][256 rows][64 cols], row = 128 B
  __shared__ __bf16 sB[2][16384];
  const int tid = threadIdx.x;
  const int w = tid >> 6, l = tid & 63;
  const int wm = w >> 2, wn = w & 3;

  // bijective XCD swizzle (all grids have nwg % 8 == 0)
  const int nwg = gridDim.x * gridDim.y;
  int wg = blockIdx.y * gridDim.x + blockIdx.x;
  wg = (wg & 7) * (nwg >> 3) + (wg >> 3);
  const int m0 = (wg / gridDim.x) << 8;
  const int n0 = (wg % gridDim.x) << 8;

  // ---- staging (global -> LDS, linear dest, pre-swizzled source) ----
  // lane l: LDS row = base + (l>>3), chunk = l&7; source chunk = (l&7)^(l>>3)
  const int lr = l >> 3;
  const int lc = (l & 7) ^ lr;
  const size_t gA = (size_t)(m0 + w * 8 + lr) * K + lc * 8;            // A issue i: +i*64 rows
  const size_t gB = (size_t)(n0 + wn * 64 + wm * 8 + lr) * K + lc * 8; // B issue j: +j*16 rows
  const int ldsA = w * 512;                  // (w*8 rows)*64
  const int ldsB = (wn * 64 + wm * 8) * 64;

  const int NTK = K >> 6;

#define STAGE_A(buf, kt, i) glds16(A + gA + (size_t)(i) * 64 * K + (size_t)(kt) * 64, &sA[buf][ldsA + (i) * 4096])
#define STAGE_B(buf, kt, j) glds16(W + gB + (size_t)(j) * 16 * K + (size_t)(kt) * 64, &sB[buf][ldsB + (j) * 1024])

  // ---- fragment reads (swizzled chunk) ----
  const int rA = (wm * 128 + (l & 15)) * 64;
  const int rB = (wn * 64 + (l & 15)) * 64;
  const int csw = l & 7;
  const int k0 = l >> 4;    // 0..3
#define LDA(buf, mi, kk) (*(const bf16x8*)&sA[buf][rA + (mi) * 1024 + ((((kk) * 4 + k0) ^ csw) << 3)])
#define LDB(buf, ni, kk) (*(const bf16x8*)&sB[buf][rB + (ni) * 1024 + ((((kk) * 4 + k0) ^ csw) << 3)])

  f32x4 acc[8][4] = {};

  // prologue: stage tile 0; order B0,B1,B2,B3, A0,A2, A1,A3 (consumption order:
  // P0 needs all B + A{0 or 2 by wm}; P1 needs A{1 or 3}).
  STAGE_B(0, 0, 0); STAGE_B(0, 0, 1); STAGE_B(0, 0, 2); STAGE_B(0, 0, 3);
  STAGE_A(0, 0, 0); STAGE_A(0, 0, 2); STAGE_A(0, 0, 1); STAGE_A(0, 0, 3);
  VMW(2);   // first 6 (all B + A0 + A2) landed; A1,A3 still flying
  SBAR();

  for (int kt = 0; kt < NTK; ++kt) {
    const int buf = kt & 1, nb = buf ^ 1;
    const bool st = (kt + 1 < NTK);
    bf16x8 a0[4], a1[4], a2[4], a3[4], b0[4], b1[4];
    // ======== P0: mi0-3 x kk0 (rows in A-issues {0,2}) ========
#pragma unroll
    for (int i = 0; i < 4; ++i) b0[i] = LDB(buf, i, 0);
#pragma unroll
    for (int i = 0; i < 4; ++i) a0[i] = LDA(buf, i, 0);
    SCHED0();
    if (st) { STAGE_B(nb, kt + 1, 0); STAGE_B(nb, kt + 1, 1); }
    SCHED0();
    if (st) { VMW(2); } else { VMW(0); }   // retire A1,A3 of current tile
    SBAR();
    LGKM0();
    __builtin_amdgcn_s_setprio(1);
#pragma unroll
    for (int mi = 0; mi < 4; ++mi)
#pragma unroll
      for (int ni = 0; ni < 4; ++ni)
        acc[mi][ni] = __builtin_amdgcn_mfma_f32_16x16x32_bf16(a0[mi], b0[ni], acc[mi][ni], 0, 0, 0);
    __builtin_amdgcn_s_setprio(0); SCHED0();
    // ======== P1: mi4-7 x kk0 (A-issues {1,3}) ========
#pragma unroll
    for (int i = 0; i < 4; ++i) a1[i] = LDA(buf, i + 4, 0);
#pragma unroll
    for (int i = 0; i < 4; ++i) b1[i] = LDB(buf, i, 1);
    SCHED0();
    if (st) { STAGE_B(nb, kt + 1, 2); STAGE_B(nb, kt + 1, 3); }
    SCHED0();
    SBAR();
    LGKM0();
    __builtin_amdgcn_s_setprio(1);
#pragma unroll
    for (int mi = 0; mi < 4; ++mi)
#pragma unroll
      for (int ni = 0; ni < 4; ++ni)
        acc[mi + 4][ni] = __builtin_amdgcn_mfma_f32_16x16x32_bf16(a1[mi], b0[ni], acc[mi + 4][ni], 0, 0, 0);
    __builtin_amdgcn_s_setprio(0); SCHED0();
    // ======== P2: mi0-3 x kk1 (b1 read in P1) ========
#pragma unroll
    for (int i = 0; i < 4; ++i) a2[i] = LDA(buf, i, 1);
    SCHED0();
    if (st) { STAGE_A(nb, kt + 1, 0); STAGE_A(nb, kt + 1, 2); }
    SCHED0();
    SBAR();
    LGKM0();
    __builtin_amdgcn_s_setprio(1);
#pragma unroll
    for (int mi = 0; mi < 4; ++mi)
#pragma unroll
      for (int ni = 0; ni < 4; ++ni)
        acc[mi][ni] = __builtin_amdgcn_mfma_f32_16x16x32_bf16(a2[mi], b1[ni], acc[mi][ni], 0, 0, 0);
    __builtin_amdgcn_s_setprio(0); SCHED0();
    // ======== P3: mi4-7 x kk1 ========
#pragma unroll
    for (int i = 0; i < 4; ++i) a3[i] = LDA(buf, i + 4, 1);
    SCHED0();
    if (st) { STAGE_A(nb, kt + 1, 1); STAGE_A(nb, kt + 1, 3); }
    SCHED0();
    if (st) { VMW(2); }   // retire next tile's B0-3 + A0,A2 (entry condition)
    SBAR();
    LGKM0();
    __builtin_amdgcn_s_setprio(1);
#pragma unroll
    for (int mi = 0; mi < 4; ++mi)
#pragma unroll
      for (int ni = 0; ni < 4; ++ni)
        acc[mi + 4][ni] = __builtin_amdgcn_mfma_f32_16x16x32_bf16(a3[mi], b1[ni], acc[mi + 4][ni], 0, 0, 0);
    __builtin_amdgcn_s_setprio(0); SCHED0();
  }

  // ---- epilogue: C/D map col=lane&15, row=(lane>>4)*4+reg ----
  const int rl = (l >> 4) << 2, cl = l & 15;
#pragma unroll
  for (int mi = 0; mi < 8; ++mi) {
#pragma unroll
    for (int ni = 0; ni < 4; ++ni) {
#pragma unroll
      for (int e = 0; e < 4; ++e) {
        const int r = m0 + (wm << 7) + mi * 16 + rl + e;
        const int cidx = n0 + (wn << 6) + ni * 16 + cl;
        const size_t idx = (size_t)r * N + cidx;
        const float vacc = acc[mi][ni][e];
        if constexpr (EPI == EPI_NONE) {
          ((__bf16*)outp)[idx] = (__bf16)vacc;
        } else if constexpr (EPI == EPI_EXP) {
          ((__bf16*)outp)[idx] = (__bf16)expf(fminf(vacc, 60.0f));
        } else if constexpr (EPI == EPI_SIG) {
          ((__bf16*)outp)[idx] = (__bf16)(1.0f / (1.0f + expf(-vacc)));
        } else if constexpr (EPI == EPI_RELU2) {
          const float rv = fmaxf(vacc, 0.0f);
          ((__bf16*)outp)[idx] = (__bf16)(rv * rv);
        } else if constexpr (EPI == EPI_RESID) {
          ((__bf16*)outp)[idx] = (__bf16)(vacc + (float)((const __bf16*)res)[idx]);
        } else if constexpr (EPI == EPI_FINAL) {
          ((float*)outp)[idx] = ((const float*)res)[idx] + (float)((const __bf16*)sig)[idx] * vacc;
        } else {  // EPI_KVR: col block 0 -> k=exp(clamp), 1 -> v, 2 -> sigmoid(r)
          const int sel = cidx >> 10;               // wave-uniform (16-aligned blocks)
          const size_t oidx = (size_t)r * 1024 + (cidx & 1023);
          if (sel == 0)      ((__bf16*)outp)[oidx] = (__bf16)expf(fminf(vacc, 60.0f));
          else if (sel == 1) ((__bf16*)const_cast<void*>(res))[oidx] = (__bf16)vacc;
          else               ((__bf16*)const_cast<void*>(sig))[oidx] = (__bf16)(1.0f / (1.0f + expf(-vacc)));
        }
      }
    }
  }
}

// ---------------- launch ----------------
extern "C" void kernel_launch(void* const* d_in, const int* in_sizes, int n_in,
                              void* d_out, int out_size, void* d_ws, size_t ws_size,
                              hipStream_t stream) {
  (void)in_sizes; (void)n_in; (void)out_size;
  const float* x    = (const float*)d_in[0];
  const float* ln1g = (const float*)d_in[1];
  const float* ln1b = (const float*)d_in[2];
  const float* ln2g = (const float*)d_in[3];
  const float* ln2b = (const float*)d_in[4];
  const float* atm  = (const float*)d_in[5];
  const float* acm  = (const float*)d_in[6];
  const float* td   = (const float*)d_in[7];
  const float* tf   = (const float*)d_in[8];
  const float* Wk   = (const float*)d_in[9];
  const float* Wv   = (const float*)d_in[10];
  const float* Wr   = (const float*)d_in[11];
  const float* Wo   = (const float*)d_in[12];
  const float* ftm  = (const float*)d_in[13];
  const float* fcm  = (const float*)d_in[14];
  const float* Fk   = (const float*)d_in[15];
  const float* Fv   = (const float*)d_in[16];
  const float* Fr   = (const float*)d_in[17];

  constexpr size_t C = 1024, T = 2048, Bs = 8, H = 4096;
  constexpr size_t NT = Bs * T;        // 16384 tokens
  constexpr size_t NTC = NT * C;       // 16M elems
  constexpr size_t CC = C * C;
  constexpr size_t CH = C * H;

  // ---- workspace layout ----
  char* p = (char*)d_ws;
  auto takeb = [&](size_t elems) { __bf16* q = (__bf16*)p; p += elems * 2; return q; };
  __bf16* wKVR = takeb(3 * CC);   // [Wk; Wv; Wr] rows stacked -> (3072, 1024)
  __bf16* wWo  = takeb(CC);
  __bf16* wFk  = takeb(CH);
  __bf16* wFv  = takeb(CH);
  __bf16* wFr  = takeb(CC);
  __bf16* Ab   = takeb(NTC);      // x1 -> x2 (in-place residual)
  __bf16* Bb   = takeb(NTC);      // xm -> srw -> sr2
  __bf16* Db   = takeb(NTC);      // v  -> xm2
  float* scA = (float*)p; p += Bs * 32 * C * 4;   // wkv carries (b,j,c)
  float* scB = (float*)p; p += Bs * 32 * C * 4;
  __bf16* kk = (__bf16*)p;        // k lives here too (dead before Fk writes kk)
  const size_t used = (size_t)(p - (char*)d_ws);
  const size_t kkcap = ws_size > used ? ws_size - used : 0;
  int chunks = 4;                                   // 32 MiB kk
  if (kkcap >= NT * H * 2)          chunks = 1;     // 128 MiB kk
  else if (kkcap >= NT * H)         chunks = 2;     // 64 MiB kk
  __bf16* Cb = kk;                 // k buffer (32 MiB) aliases kk region
  __bf16* sr  = (__bf16*)d_out;    // sigmoid(r) borrows d_out until ln2 overwrites it
  float*  x3  = (float*)d_out;

  auto cvt = [&](const float* src, size_t n, __bf16* dst) {
    const int n4 = (int)(n / 4);
    cvt_bf16<<<dim3((n4 + 255) / 256), dim3(256), 0, stream>>>(src, dst, n4);
  };
  cvt(Wk, CC, wKVR); cvt(Wv, CC, wKVR + CC); cvt(Wr, CC, wKVR + 2 * CC);
  cvt(Wo, CC, wWo); cvt(Fk, CH, wFk); cvt(Fv, CH, wFv); cvt(Fr, CC, wFr);

  const dim3 blk(256), blkG(512);

  // x1 = ln1(x)            [Ab]
  ln_kernel<float, __bf16><<<dim3((unsigned)NT), blk, 0, stream>>>(x, ln1g, ln1b, Ab);
  // xm = mix(x1)           [Bb]
  mix_kernel<__bf16><<<dim3((unsigned)(NTC / 1024)), blk, 0, stream>>>(Ab, atm, acm, Bb);
  // fused: k=exp(min(.,60)) [Cb], v [Db], sigmoid(r) [sr]
  gemmk<EPI_KVR><<<dim3(12, 64), blkG, 0, stream>>>(Bb, wKVR, Cb, Db, sr, 3072, 1024);
  // wkv: chunk partials -> carry scan -> apply (srw = sigmoid(r)*y into Bb)
  wkv_part<<<dim3(1024), blk, 0, stream>>>(Cb, Db, td, scA, scB);
  wkv_scan<<<dim3(32), blk, 0, stream>>>(td, scA, scB);
  wkv_apply<<<dim3(1024), blk, 0, stream>>>(Cb, Db, sr, td, tf, scA, scB, Bb);
  // x2 = x1 + srw@Wo^T     [Ab in-place]
  gemmk<EPI_RESID><<<dim3(4, 64), blkG, 0, stream>>>(Bb, wWo, Ab, Ab, nullptr, 1024, 1024);
  // x3 = ln2(x2)           [d_out, fp32]
  ln_kernel<__bf16, float><<<dim3((unsigned)NT), blk, 0, stream>>>(Ab, ln2g, ln2b, x3);
  // xm2 = mix(x3)          [Db]
  mix_kernel<float><<<dim3((unsigned)(NTC / 1024)), blk, 0, stream>>>(x3, ftm, fcm, Db);
  // sr2 = sigmoid(xm2@Fr^T) [Bb]
  gemmk<EPI_SIG><<<dim3(4, 64), blkG, 0, stream>>>(Db, wFr, Bb, nullptr, nullptr, 1024, 1024);
  // FFN: kk = relu(xm2@Fk^T)^2 [kk], out = x3 + sr2 * (kk@Fv^T)  (chunked if ws small)
  const size_t Mc = NT / chunks;
  for (int ch = 0; ch < chunks; ++ch) {
    const size_t ro = (size_t)ch * Mc;
    gemmk<EPI_RELU2><<<dim3(16, (unsigned)(Mc / 256)), blkG, 0, stream>>>(
        Db + ro * C, wFk, kk, nullptr, nullptr, 4096, 1024);
    gemmk<EPI_FINAL><<<dim3(4, (unsigned)(Mc / 256)), blkG, 0, stream>>>(
        kk, wFv, (float*)d_out + ro * C, (const float*)d_out + ro * C,
        Bb + ro * C, 1024, 4096);
  }
}